// Round 11
// baseline (184.500 us; speedup 1.0000x reference)
//
#include <hip/hip_runtime.h>
#include <hip/hip_fp16.h>

#define NC_MEM 64
#define NC_IMG 64
#define NC     128
#define B_     32
#define H_     64
#define W_     96
#define HW_    (H_ * W_)      // 6144
#define P_TILE 64             // 64-px tiles, 256-thread blocks
#define NTILES (HW_ / P_TILE) // 96
#define FS     520            // frag stride in ushorts: 512 + 8 pad
#define FOFF(pt, ks) ((((pt) * 4) + (ks)) * FS)
// rotated block placement, applied on every write and read (pure relabeling)
#define XOFF(pt, ks, blk) (FOFF(pt, ks) + ((((blk) + (pt)) & 63) << 3))

typedef _Float16 f16x8 __attribute__((ext_vector_type(8)));
typedef __attribute__((ext_vector_type(4))) float f32x4;

struct w8 { f32x4 a, b; };

__device__ inline unsigned pk2h(float a, float b) {
    __half2 h = __floats2half2_rn(a, b);
    return *(const unsigned*)&h;
}

// Raw-W fragment load: the A-fragment for (l,mt,ks) is 8 CONSECUTIVE floats
// of Ws per lane (inverse map verified by v10's coalesced prep, which passed):
//   o = mt*16 + (lane&15), c = ks*32 + (lane>>4)*8 + j, j=0..7
// Two dwordx4 per lane -- same 32 B/lane the old WA_HI+WA_LO table reads cost.
__device__ inline w8 ldw(const float* __restrict__ Ws, int l, int mt, int ks, int lane) {
    const float* s = Ws + (((size_t)(l * 128 + mt * 16 + (lane & 15))) * 128
                           + ks * 32 + ((lane >> 4) << 3));
    w8 r; r.a = *(const f32x4*)s; r.b = *(const f32x4*)(s + 4); return r;
}
// In-register hi/lo split, bit-identical to prep's __float2half_rn sequence
// ((_Float16) cast = v_cvt_f16_f32 RNE).
__device__ inline void cvtw(const w8& w, f16x8& hi, f16x8& lo) {
#pragma unroll
    for (int j = 0; j < 8; ++j) {
        float x = (j < 4) ? w.a[j] : w.b[j - 4];
        _Float16 h = (_Float16)x;
        hi[j] = h;
        lo[j] = (_Float16)(x - (float)h);
    }
}

// LDS-only barrier (orders ds ops without draining vmcnt); proven safe in v6.
// W loads issued before a barrier stay in flight; conversion after the
// barrier carries the vmcnt wait to the use site (sched_barrier pins order).
__device__ inline void bar_lds() {
    __builtin_amdgcn_sched_barrier(0);
    asm volatile("s_waitcnt lgkmcnt(0)" ::: "memory");
    __builtin_amdgcn_s_barrier();
    asm volatile("" ::: "memory");
    __builtin_amdgcn_sched_barrier(0);
}

// ---------------------------------------------------------------------------
// fused_main v11: SINGLE DISPATCH. prep is gone --
//  * W hi/lo split moved in-register (ldw/cvtw above; same bytes, same math);
//  * um decode per wave: 32-byte probe + __any ballot;
//  * xf (4x4 adjugate inverse + matmul) computed by wave 0 only (the FTL
//    stagers), overlapped under the stage loads' L2 latency.
// v10 showed prep's store pattern was not the cost; what remained was its
// fixed cost: a second serialized dispatch + workspace round-trip. This
// removes launch + gap + graph node (~6-9 us of dur_us) for ~0.5 us/wave of
// added VALU (20 fragment-pair conversions) that hides under existing stalls.
// Compute structure is v8 VERBATIM (best measured: 50 us dispatch).
// launch_bounds(256,3): reg cap 170 so the prologue peak (~90: stage v[8] +
// xf temps) ALLOCATES instead of spilling (v5/v9 lesson: the allocator
// targeting 8 waves/SIMD spills everything past 64 regs); 3 waves/SIMD floor
// = 12 waves/CU, still above the measured 32% occupancy plateau.
// ---------------------------------------------------------------------------
__global__ __launch_bounds__(256, 3)
void fused_main(const float* __restrict__ img, const float* __restrict__ mem,
                const int* __restrict__ mem_idx, const float* __restrict__ bs,
                const float* __restrict__ Ws,
                const float* __restrict__ prev_ext, const float* __restrict__ cur_ext,
                const unsigned char* __restrict__ um_raw,
                float* __restrict__ out) {
    __shared__ unsigned short xh[16 * FS]; // 16640 B

    const int t   = threadIdx.x;
    const int b   = blockIdx.y;
    const int hw0 = blockIdx.x * P_TILE;

    const int w    = t >> 6;        // 0..3
    const int lane = t & 63;
    const int wq   = lane >> 4;
    const int lm   = lane & 15;
    const int mt0  = 2 * w;         // wave's mt pair: 0,2,4,6
    const int mt2  = 4 + w;         // wave's L2 mt: 4..7

    // ---- um decode (per wave; wave-uniform result) + mem gather index ----
    const int mi = mem_idx[b];
    bool flag = (lane < 32) && (lane & 3) && (um_raw[lane] != 0);
    bool is_bool = __any(flag);
    const bool umb = is_bool ? (um_raw[b] != 0) : (((const int*)um_raw)[b] != 0);

    // ---- stage: global f32 -> (xf compute + FTL) -> f16 in LDS ----
    {
        const int q   = t & 15;        // px quad: px = 4q..4q+3 (0..63)
        const int og  = t >> 4;        // channel octet 0..15
        const int px0 = hw0 + q * 4;
        const int pt  = q >> 2;        // 0..3
        if (umb) {
            const int c0 = og * 8;     // 8 channels, one side of 64
            const float* basep = (c0 < NC_MEM)
                ? (mem + ((size_t)mi * NC_MEM + c0) * HW_ + px0)
                : (img + ((size_t)b * NC_IMG + (c0 - NC_MEM)) * HW_ + px0);
            f32x4 v[8];
#pragma unroll
            for (int cc = 0; cc < 8; ++cc)
                v[cc] = *(const f32x4*)(basep + (size_t)cc * HW_);
            if (og < 4) {              // == wave 0: compute xf, then FTL
                // xf = cur_ext[b] * inv(prev_ext[mi]) -- adjugate closed form,
                // arithmetic verbatim from the old prep (issued after the
                // stage loads so the ~50-op chain hides under their latency)
                float a[16], cv[16];
                const float* pe = prev_ext + (size_t)mi * 16;
                const float* ce = cur_ext + (size_t)b * 16;
#pragma unroll
                for (int j = 0; j < 4; ++j) {
                    *(f32x4*)&a[j * 4]  = *(const f32x4*)(pe + j * 4);
                    *(f32x4*)&cv[j * 4] = *(const f32x4*)(ce + j * 4);
                }
                float s0 = a[0]*a[5]  - a[1]*a[4];
                float s1 = a[0]*a[6]  - a[2]*a[4];
                float s2 = a[0]*a[7]  - a[3]*a[4];
                float s3 = a[1]*a[6]  - a[2]*a[5];
                float s4 = a[1]*a[7]  - a[3]*a[5];
                float s5 = a[2]*a[7]  - a[3]*a[6];
                float c5 = a[10]*a[15] - a[11]*a[14];
                float c4 = a[9]*a[15]  - a[11]*a[13];
                float c3 = a[9]*a[14]  - a[10]*a[13];
                float c2 = a[8]*a[15]  - a[11]*a[12];
                float c1 = a[8]*a[14]  - a[10]*a[12];
                float c0f = a[8]*a[13] - a[9]*a[12];
                float det = s0*c5 - s1*c4 + s2*c3 + s3*c2 - s4*c1 + s5*c0f;
                float id = 1.0f / det;
                float inv[16];
                inv[0]  = ( a[5]*c5  - a[6]*c4  + a[7]*c3)  * id;
                inv[1]  = (-a[1]*c5  + a[2]*c4  - a[3]*c3)  * id;
                inv[2]  = ( a[13]*s5 - a[14]*s4 + a[15]*s3) * id;
                inv[3]  = (-a[9]*s5  + a[10]*s4 - a[11]*s3) * id;
                inv[4]  = (-a[4]*c5  + a[6]*c2  - a[7]*c1)  * id;
                inv[5]  = ( a[0]*c5  - a[2]*c2  + a[3]*c1)  * id;
                inv[6]  = (-a[12]*s5 + a[14]*s2 - a[15]*s1) * id;
                inv[7]  = ( a[8]*s5  - a[10]*s2 + a[11]*s1) * id;
                inv[8]  = ( a[4]*c4  - a[5]*c2  + a[7]*c0f) * id;
                inv[9]  = (-a[0]*c4  + a[1]*c2  - a[3]*c0f) * id;
                inv[10] = ( a[12]*s4 - a[13]*s2 + a[15]*s0) * id;
                inv[11] = (-a[8]*s4  + a[9]*s2  - a[11]*s0) * id;
                inv[12] = (-a[4]*c3  + a[5]*c1  - a[6]*c0f) * id;
                inv[13] = ( a[0]*c3  - a[1]*c1  + a[2]*c0f) * id;
                inv[14] = (-a[12]*s3 + a[13]*s1 - a[14]*s0) * id;
                inv[15] = ( a[8]*s3  - a[9]*s1  + a[10]*s0) * id;
                float xfv[16];
#pragma unroll
                for (int i = 0; i < 4; ++i)
#pragma unroll
                    for (int j2 = 0; j2 < 4; ++j2) {
                        float s = 0.f;
#pragma unroll
                        for (int k = 0; k < 4; ++k)
                            s += cv[i * 4 + k] * inv[k * 4 + j2];
                        xfv[i * 4 + j2] = s;
                    }
                // FTL on channel groups 0..7 (c < 32)
#pragma unroll
                for (int sg = 0; sg < 2; ++sg) {
#pragma unroll
                    for (int i = 0; i < 4; ++i) {
                        float a0 = v[4*sg+0][i], a1 = v[4*sg+1][i];
                        float a2 = v[4*sg+2][i], a3 = v[4*sg+3][i];
                        v[4*sg+0][i] = xfv[0]*a0  + xfv[1]*a1  + xfv[2]*a2  + xfv[3]*a3;
                        v[4*sg+1][i] = xfv[4]*a0  + xfv[5]*a1  + xfv[6]*a2  + xfv[7]*a3;
                        v[4*sg+2][i] = xfv[8]*a0  + xfv[9]*a1  + xfv[10]*a2 + xfv[11]*a3;
                        v[4*sg+3][i] = xfv[12]*a0 + xfv[13]*a1 + xfv[14]*a2 + xfv[15]*a3;
                    }
                }
            }
            const int bk0 = (og & 3) * 16 + (q & 3) * 4;
#pragma unroll
            for (int i = 0; i < 4; ++i) {
                uint4 pk;
                pk.x = pk2h(v[0][i], v[1][i]);
                pk.y = pk2h(v[2][i], v[3][i]);
                pk.z = pk2h(v[4][i], v[5][i]);
                pk.w = pk2h(v[6][i], v[7][i]);
                *(uint4*)&xh[XOFF(pt, og >> 2, bk0 + i)] = pk;
            }
        } else {
            // img channels only (groups 16..31); mem rows never read in L0
            const int gg = 16 + og;
            const int c0 = gg * 4 - NC_MEM;  // img channel 0..60
            f32x4 u[4];
#pragma unroll
            for (int cc = 0; cc < 4; ++cc)
                u[cc] = *(const f32x4*)(img + ((size_t)b * NC_IMG + c0 + cc) * HW_ + px0);
            const int bk0 = ((gg & 7) >> 1) * 16 + (q & 3) * 4;
            const int hoff = (gg & 1) * 4;
#pragma unroll
            for (int i = 0; i < 4; ++i)
                *(uint2*)&xh[XOFF(pt, gg >> 3, bk0 + i) + hoff] =
                    make_uint2(pk2h(u[0][i], u[1][i]), pk2h(u[2][i], u[3][i]));
        }
    }

    // ---- B-fragment read pointers: computed once, valid for all layers ----
    const unsigned short* bp[4];
#pragma unroll
    for (int nt = 0; nt < 4; ++nt)
        bp[nt] = &xh[XOFF(nt, 0, lane)];

    // ---- prefetch layer-0 A frags (raw f32) before the barrier ----
    const int kpa = umb ? 0 : 2, kpb = umb ? 1 : 3;
    w8 pw0 = ldw(Ws, 0, mt0,     kpa, lane);
    w8 pw1 = ldw(Ws, 0, mt0 + 1, kpa, lane);
    w8 pw2 = ldw(Ws, 0, mt0,     kpb, lane);
    w8 pw3 = ldw(Ws, 0, mt0 + 1, kpb, lane);

    bar_lds();   // B1: stage complete (W loads stay in flight)

    f32x4 acc[2][4];

    auto run_ks = [&](int ks, f16x8 ah0, f16x8 al0, f16x8 ah1, f16x8 al1) {
#pragma unroll
        for (int nt = 0; nt < 4; ++nt) {
            f16x8 bh = *(const f16x8*)(bp[nt] + ks * FS);
            acc[0][nt] = __builtin_amdgcn_mfma_f32_16x16x32_f16(ah0, bh, acc[0][nt], 0, 0, 0);
            acc[1][nt] = __builtin_amdgcn_mfma_f32_16x16x32_f16(ah1, bh, acc[1][nt], 0, 0, 0);
            acc[0][nt] = __builtin_amdgcn_mfma_f32_16x16x32_f16(al0, bh, acc[0][nt], 0, 0, 0);
            acc[1][nt] = __builtin_amdgcn_mfma_f32_16x16x32_f16(al1, bh, acc[1][nt], 0, 0, 0);
        }
    };
    auto run_ks_w = [&](int l, int ks) {
        w8 wa = ldw(Ws, l, mt0, ks, lane), wb = ldw(Ws, l, mt0 + 1, ks, lane);
        f16x8 ah0, al0, ah1, al1;
        cvtw(wa, ah0, al0); cvtw(wb, ah1, al1);
        run_ks(ks, ah0, al0, ah1, al1);
    };
    auto writeback = [&]() {
#pragma unroll
        for (int mi2 = 0; mi2 < 2; ++mi2) {
            const int mt = mt0 + mi2;
            const int ks2 = mt >> 1;
            const int lane_f = ((mt & 1) * 2 + (wq >> 1)) * 16 + lm;
            const int j0 = (wq & 1) * 4;
#pragma unroll
            for (int nt = 0; nt < 4; ++nt) {
                float v0 = fmaxf(acc[mi2][nt][0], 0.f);
                float v1 = fmaxf(acc[mi2][nt][1], 0.f);
                float v2 = fmaxf(acc[mi2][nt][2], 0.f);
                float v3 = fmaxf(acc[mi2][nt][3], 0.f);
                *(uint2*)&xh[XOFF(nt, ks2, lane_f) + j0] =
                    make_uint2(pk2h(v0, v1), pk2h(v2, v3));
            }
        }
    };

    // ---------------- layer 0 ----------------
#pragma unroll
    for (int mi2 = 0; mi2 < 2; ++mi2) {
        f32x4 bv = *(const f32x4*)&bs[0 * NC + (mt0 + mi2) * 16 + wq * 4];
#pragma unroll
        for (int nt = 0; nt < 4; ++nt) acc[mi2][nt] = bv;
    }
    {
        f16x8 p0h, p0l, p1h, p1l, p2h, p2l, p3h, p3l;
        cvtw(pw0, p0h, p0l); cvtw(pw1, p1h, p1l);
        cvtw(pw2, p2h, p2l); cvtw(pw3, p3h, p3l);
        __builtin_amdgcn_s_setprio(1);
        if (umb) {
            run_ks(0, p0h, p0l, p1h, p1l);
            run_ks(1, p2h, p2l, p3h, p3l);
            run_ks_w(0, 2);
            run_ks_w(0, 3);
        } else {
            run_ks(2, p0h, p0l, p1h, p1l);
            run_ks(3, p2h, p2l, p3h, p3l);
        }
        __builtin_amdgcn_s_setprio(0);
    }
    // prefetch layer-1 ks0/ks1 (raw) across the barriers
    w8 qw0 = ldw(Ws, 1, mt0, 0, lane), qw1 = ldw(Ws, 1, mt0 + 1, 0, lane);
    w8 qw2 = ldw(Ws, 1, mt0, 1, lane), qw3 = ldw(Ws, 1, mt0 + 1, 1, lane);
    bar_lds();              // B2: all layer-0 reads of xh done
    writeback();            // overwrite xh in place
    bar_lds();              // B3: layer-0 output visible

    // ---------------- layer 1 ----------------
#pragma unroll
    for (int mi2 = 0; mi2 < 2; ++mi2) {
        f32x4 bv = *(const f32x4*)&bs[1 * NC + (mt0 + mi2) * 16 + wq * 4];
#pragma unroll
        for (int nt = 0; nt < 4; ++nt) acc[mi2][nt] = bv;
    }
    {
        f16x8 q0h, q0l, q1h, q1l, q2h, q2l, q3h, q3l;
        cvtw(qw0, q0h, q0l); cvtw(qw1, q1h, q1l);
        cvtw(qw2, q2h, q2l); cvtw(qw3, q3h, q3l);
        __builtin_amdgcn_s_setprio(1);
        run_ks(0, q0h, q0l, q1h, q1l);
        run_ks(1, q2h, q2l, q3h, q3l);
        run_ks_w(1, 2);
        run_ks_w(1, 3);
        __builtin_amdgcn_s_setprio(0);
    }
    // prefetch ALL layer-2 A frags (raw; single mt per wave -> 4 pairs)
    w8 rw0 = ldw(Ws, 2, mt2, 0, lane), rw1 = ldw(Ws, 2, mt2, 1, lane);
    w8 rw2 = ldw(Ws, 2, mt2, 2, lane), rw3 = ldw(Ws, 2, mt2, 3, lane);
    bar_lds();              // B4: all layer-1 reads of xh done
    writeback();
    bar_lds();              // B5: layer-1 output visible

    // ---------------- layer 2: out channels 64..127 only ----------------
    {
        f32x4 a2[4];
        f32x4 bv = *(const f32x4*)&bs[2 * NC + mt2 * 16 + wq * 4];
#pragma unroll
        for (int nt = 0; nt < 4; ++nt) a2[nt] = bv;
        auto run2 = [&](int ks, f16x8 ah, f16x8 al) {
#pragma unroll
            for (int nt = 0; nt < 4; ++nt) {
                f16x8 bh = *(const f16x8*)(bp[nt] + ks * FS);
                a2[nt] = __builtin_amdgcn_mfma_f32_16x16x32_f16(ah, bh, a2[nt], 0, 0, 0);
                a2[nt] = __builtin_amdgcn_mfma_f32_16x16x32_f16(al, bh, a2[nt], 0, 0, 0);
            }
        };
        f16x8 r0h, r0l, r1h, r1l, r2h, r2l, r3h, r3l;
        cvtw(rw0, r0h, r0l); cvtw(rw1, r1h, r1l);
        cvtw(rw2, r2h, r2l); cvtw(rw3, r3h, r3l);
        __builtin_amdgcn_s_setprio(1);
        run2(0, r0h, r0l);
        run2(1, r1h, r1l);
        run2(2, r2h, r2l);
        run2(3, r3h, r3l);
        __builtin_amdgcn_s_setprio(0);
        const int oc0 = mt2 * 16 + wq * 4 - 64; // 0..60
#pragma unroll
        for (int nt = 0; nt < 4; ++nt) {
            float* dst = out + ((size_t)b * 64 + oc0) * HW_ + hw0 + nt * 16 + lm;
#pragma unroll
            for (int r = 0; r < 4; ++r)
                __builtin_nontemporal_store(a2[nt][r], dst + (size_t)r * HW_);
        }
    }
}

extern "C" void kernel_launch(void* const* d_in, const int* in_sizes, int n_in,
                              void* d_out, int out_size, void* d_ws, size_t ws_size,
                              hipStream_t stream) {
    const float* img  = (const float*)d_in[0];
    const float* mem  = (const float*)d_in[1];
    const float* pext = (const float*)d_in[2];
    const float* cext = (const float*)d_in[3];
    const int*   midx = (const int*)d_in[4];
    const unsigned char* umem = (const unsigned char*)d_in[5];
    const float* Ws   = (const float*)d_in[6];
    const float* bs   = (const float*)d_in[7];
    float* out = (float*)d_out;
    (void)d_ws; (void)ws_size;

    hipLaunchKernelGGL(fused_main, dim3(NTILES, B_), dim3(256), 0, stream,
                       img, mem, midx, bs, Ws, pext, cext, umem, out);
}